// Round 3
// baseline (243.303 us; speedup 1.0000x reference)
//
#include <hip/hip_runtime.h>

// DecoderAttention: only edges into the B=64 global nodes contribute (q is zero
// elsewhere and only out[glob_idx] is read) -> ~512 of 320000 edges matter.
// Round-2 change: edge-PARALLEL score/value kernels (one block per edge slot)
// instead of one block per node with a serial edge loop (round-1 was 1.7%
// occupancy / 2% VALUBusy, pure latency-bound).

#define Dm 256
#define Hh 4
#define CAP 32   // max in-degree of a global node we support; deg ~ Poisson(8)

// init inverse map, bucket counters, and the value accumulator (ws is poisoned)
__global__ void k_init(int* __restrict__ inv, int nv, int* __restrict__ bcnt,
                       int b, float* __restrict__ o) {
    int i = blockIdx.x * blockDim.x + threadIdx.x;
    if (i < nv) inv[i] = -1;
    if (i < b) bcnt[i] = 0;
    if (i < b * Dm) o[i] = 0.f;
}

// One block per global row: Q[b][j] = dot(query[b], WQ[j]); also build inverse map.
__global__ __launch_bounds__(256)
void k_qproj(const float* __restrict__ query, const float* __restrict__ WQ,
             const int* __restrict__ glob_idx, float* __restrict__ Q,
             int* __restrict__ inv) {
    int bb = blockIdx.x;
    int j = threadIdx.x;
    const float4* qr = reinterpret_cast<const float4*>(query + (size_t)bb * Dm);
    const float4* wr = reinterpret_cast<const float4*>(WQ + (size_t)j * Dm);
    float acc = 0.f;
#pragma unroll
    for (int c = 0; c < Dm / 4; ++c) {
        float4 a = qr[c], w = wr[c];
        acc += a.x * w.x + a.y * w.y + a.z * w.z + a.w * w.w;
    }
    Q[bb * Dm + j] = acc;
    if (j == 0) inv[glob_idx[bb]] = bb;
}

__global__ void k_compact(const int* __restrict__ src, const int* __restrict__ dst,
                          const int* __restrict__ inv, int* __restrict__ bcnt,
                          int* __restrict__ bucket, int ne) {
    int e = blockIdx.x * blockDim.x + threadIdx.x;
    if (e >= ne) return;
    int ii = inv[dst[e]];
    if (ii >= 0) {
        int pos = atomicAdd(&bcnt[ii], 1);
        if (pos < CAP) bucket[ii * CAP + pos] = src[e];
    }
}

// One block per (global node b, edge slot e). 256 thr = 4 waves = 4 heads.
// Score s[b][e][h] = (q[b,h] . k[src]) / sqrt(DK), k row computed on the fly.
__global__ __launch_bounds__(256)
void k_score(const float* __restrict__ x, const float* __restrict__ WK,
             const float* __restrict__ Q, const int* __restrict__ bcnt,
             const int* __restrict__ bucket, float* __restrict__ sbuf) {
    int b = blockIdx.x / CAP, e = blockIdx.x % CAP;
    int deg = min(bcnt[b], CAP);
    if (e >= deg) return;
    int t = threadIdx.x, h = t >> 6, lane = t & 63;
    __shared__ float4 sx[Dm / 4];
    int sv = bucket[b * CAP + e];
    if (t < Dm / 4) sx[t] = reinterpret_cast<const float4*>(x + (size_t)sv * Dm)[t];
    __syncthreads();
    const float4* wk = reinterpret_cast<const float4*>(WK + (size_t)t * Dm);
    float acc = 0.f;
#pragma unroll
    for (int c = 0; c < Dm / 4; ++c) {
        float4 a = sx[c], w = wk[c];
        acc += a.x * w.x + a.y * w.y + a.z * w.z + a.w * w.w;
    }
    float p = acc * Q[b * Dm + t];   // k[sv][t] * q[b][t]; reduce over this head's 64 dims
#pragma unroll
    for (int off = 32; off >= 1; off >>= 1) p += __shfl_xor(p, off, 64);
    if (lane == 0) sbuf[(b * CAP + e) * Hh + h] = p * 0.125f;  // 1/sqrt(64)
}

// One block, 256 threads: thread t handles (b = t/4, h = t%4); deg <= 32.
__global__ void k_softmax(const int* __restrict__ bcnt, float* __restrict__ sbuf) {
    int t = threadIdx.x;
    int b = t / Hh, h = t % Hh;
    int deg = min(bcnt[b], CAP);
    if (deg == 0) return;
    float m = -INFINITY;
    for (int e = 0; e < deg; ++e) m = fmaxf(m, sbuf[(b * CAP + e) * Hh + h]);
    float dn = 0.f;
    for (int e = 0; e < deg; ++e) dn += expf(sbuf[(b * CAP + e) * Hh + h] - m);
    float r = 1.f / dn;
    for (int e = 0; e < deg; ++e) {
        float* p = &sbuf[(b * CAP + e) * Hh + h];
        *p = expf(*p - m) * r;       // alpha, fully normalized
    }
}

// One block per (b, e): v row on the fly, atomically accumulate alpha * v into o[b].
__global__ __launch_bounds__(256)
void k_vaggr(const float* __restrict__ x, const float* __restrict__ WV,
             const int* __restrict__ bcnt, const int* __restrict__ bucket,
             const float* __restrict__ sbuf, float* __restrict__ o) {
    int b = blockIdx.x / CAP, e = blockIdx.x % CAP;
    int deg = min(bcnt[b], CAP);
    if (e >= deg) return;
    int t = threadIdx.x, h = t >> 6;
    __shared__ float4 sx[Dm / 4];
    int sv = bucket[b * CAP + e];
    if (t < Dm / 4) sx[t] = reinterpret_cast<const float4*>(x + (size_t)sv * Dm)[t];
    __syncthreads();
    const float4* wv = reinterpret_cast<const float4*>(WV + (size_t)t * Dm);
    float acc = 0.f;
#pragma unroll
    for (int c = 0; c < Dm / 4; ++c) {
        float4 a = sx[c], w = wv[c];
        acc += a.x * w.x + a.y * w.y + a.z * w.z + a.w * w.w;
    }
    atomicAdd(&o[b * Dm + t], sbuf[(b * CAP + e) * Hh + h] * acc);
}

// Output projection: r[b][t] = dot(o[b], WO[t]). deg==0 rows stay 0 (matches ref).
__global__ __launch_bounds__(256)
void k_out(const float* __restrict__ o, const float* __restrict__ WO,
           float* __restrict__ out) {
    int b = blockIdx.x, t = threadIdx.x;
    __shared__ float4 so[Dm / 4];
    if (t < Dm / 4) so[t] = reinterpret_cast<const float4*>(o + (size_t)b * Dm)[t];
    __syncthreads();
    const float4* wo = reinterpret_cast<const float4*>(WO + (size_t)t * Dm);
    float r = 0.f;
#pragma unroll
    for (int c = 0; c < Dm / 4; ++c) {
        float4 a = so[c], w = wo[c];
        r += a.x * w.x + a.y * w.y + a.z * w.z + a.w * w.w;
    }
    out[b * Dm + t] = r;
}

extern "C" void kernel_launch(void* const* d_in, const int* in_sizes, int n_in,
                              void* d_out, int out_size, void* d_ws, size_t ws_size,
                              hipStream_t stream) {
    const float* query = (const float*)d_in[0];
    const float* x     = (const float*)d_in[1];
    const float* WQ    = (const float*)d_in[2];
    const float* WK    = (const float*)d_in[3];
    const float* WV    = (const float*)d_in[4];
    const float* WO    = (const float*)d_in[5];
    const int*   src   = (const int*)d_in[6];
    const int*   dst   = (const int*)d_in[7];
    const int*   glob  = (const int*)d_in[8];

    int B  = in_sizes[8];
    int NV = in_sizes[1] / Dm;
    int NE = in_sizes[6];

    // ws layout (floats/ints, all 16B-aligned offsets):
    // Q[B*Dm] | inv[NV] | bcnt[B] | bucket[B*CAP] | sbuf[B*CAP*Hh] | o[B*Dm]
    float* Q      = (float*)d_ws;
    int*   inv    = (int*)(Q + (size_t)B * Dm);
    int*   bcnt   = inv + NV;
    int*   bucket = bcnt + B;
    float* sbuf   = (float*)(bucket + (size_t)B * CAP);
    float* o      = sbuf + (size_t)B * CAP * Hh;
    float* out    = (float*)d_out;

    int initN = NV > B * Dm ? NV : B * Dm;
    k_init<<<(initN + 255) / 256, 256, 0, stream>>>(inv, NV, bcnt, B, o);
    k_qproj<<<B, 256, 0, stream>>>(query, WQ, glob, Q, inv);
    k_compact<<<(NE + 255) / 256, 256, 0, stream>>>(src, dst, inv, bcnt, bucket, NE);
    k_score<<<B * CAP, 256, 0, stream>>>(x, WK, Q, bcnt, bucket, sbuf);
    k_softmax<<<1, B * Hh, 0, stream>>>(bcnt, sbuf);
    k_vaggr<<<B * CAP, 256, 0, stream>>>(x, WV, bcnt, bucket, sbuf, o);
    k_out<<<B, 256, 0, stream>>>(o, WO, out);
}

// Round 4
// 165.864 us; speedup vs baseline: 1.4669x; 1.4669x over previous
//
#include <hip/hip_runtime.h>

// DecoderAttention: only edges into the B=64 global nodes contribute (~512 of
// 320000). Round-4: all weight reads are wave-per-row COALESCED (round-3 was
// latency-bound on lane-strided W reads: VALUBusy 1.5%). Softmax is computed
// without max-subtraction (scores |s|<~3, mathematically identical), letting
// score+V+aggregation fuse into one kernel via exp-weighted atomics.

#define Dm 256
#define Hh 4
#define CAP 32   // max supported in-degree of a global node; deg ~ Poisson(8)

__device__ __forceinline__ float dot4(float4 a, float4 b) {
    return a.x * b.x + a.y * b.y + a.z * b.z + a.w * b.w;
}

// init inverse map, bucket counters, o-accumulator, denominators (ws is poisoned)
__global__ void k_init(int* __restrict__ inv, int nv, int* __restrict__ bcnt,
                       int b, float* __restrict__ oacc, float* __restrict__ den) {
    int i = blockIdx.x * blockDim.x + threadIdx.x;
    if (i < nv) inv[i] = -1;
    if (i < b) bcnt[i] = 0;
    if (i < b * Dm) oacc[i] = 0.f;
    if (i < b * Hh) den[i] = 0.f;
}

// One block per global row. Wave w computes Q rows w*64..w*64+63, coalesced:
// per row, the wave loads the whole WQ row (64 lanes x float4), dots with the
// lane-private query fragment, butterfly-reduces; lane r keeps row r's value.
__global__ __launch_bounds__(256)
void k_qproj(const float* __restrict__ query, const float* __restrict__ WQ,
             const int* __restrict__ glob_idx, float* __restrict__ Q,
             int* __restrict__ inv) {
    int bb = blockIdx.x, t = threadIdx.x, w = t >> 6, lane = t & 63;
    float4 xa = reinterpret_cast<const float4*>(query + (size_t)bb * Dm)[lane];
    float keep = 0.f;
#pragma unroll 4
    for (int r = 0; r < 64; ++r) {
        float4 ww = reinterpret_cast<const float4*>(WQ + (size_t)(w * 64 + r) * Dm)[lane];
        float p = dot4(ww, xa);
#pragma unroll
        for (int off = 1; off <= 32; off <<= 1) p += __shfl_xor(p, off, 64);
        if (lane == r) keep = p;
    }
    Q[bb * Dm + w * 64 + lane] = keep;   // coalesced
    if (t == 0) inv[glob_idx[bb]] = bb;
}

__global__ void k_compact(const int* __restrict__ src, const int* __restrict__ dst,
                          const int* __restrict__ inv, int* __restrict__ bcnt,
                          int* __restrict__ bucket, int ne) {
    int e = blockIdx.x * blockDim.x + threadIdx.x;
    if (e >= ne) return;
    int ii = inv[dst[e]];
    if (ii >= 0) {
        int pos = atomicAdd(&bcnt[ii], 1);
        if (pos < CAP) bucket[ii * CAP + pos] = src[e];
    }
}

// One block per (global node b, edge slot e). Wave w owns head w entirely:
//   score: acc_l = sum_r q[row]*partial_r(l) over the head's 64 WK rows
//          (reduction linearity -> ONE butterfly per wave), s = acc/8
//   value: per WV row, coalesced load + dot + butterfly; lane r keeps row r;
//          one 64-lane atomicAdd of exp(s)*v into oacc; denom += exp(s).
__global__ __launch_bounds__(256)
void k_kv(const float* __restrict__ x, const float* __restrict__ WK,
          const float* __restrict__ WV, const float* __restrict__ Q,
          const int* __restrict__ bcnt, const int* __restrict__ bucket,
          float* __restrict__ oacc, float* __restrict__ den) {
    int b = blockIdx.x / CAP, e = blockIdx.x % CAP;
    int deg = min(bcnt[b], CAP);
    if (e >= deg) return;
    int t = threadIdx.x, w = t >> 6, lane = t & 63;
    int sv = bucket[b * CAP + e];
    float4 xa = reinterpret_cast<const float4*>(x + (size_t)sv * Dm)[lane];  // coalesced, all rows reuse it
    const float* qrow = Q + b * Dm + w * 64;   // wave-uniform -> scalar loads

    float acc = 0.f;
#pragma unroll 8
    for (int r = 0; r < 64; ++r) {
        float4 kw = reinterpret_cast<const float4*>(WK + (size_t)(w * 64 + r) * Dm)[lane];
        acc += qrow[r] * dot4(kw, xa);
    }
#pragma unroll
    for (int off = 1; off <= 32; off <<= 1) acc += __shfl_xor(acc, off, 64);
    float wexp = __expf(acc * 0.125f);         // 1/sqrt(64); |s| small -> no max needed
    if (lane == 0) atomicAdd(&den[b * Hh + w], wexp);

    float keep = 0.f;
#pragma unroll 4
    for (int r = 0; r < 64; ++r) {
        float4 vw = reinterpret_cast<const float4*>(WV + (size_t)(w * 64 + r) * Dm)[lane];
        float p = dot4(vw, xa);
#pragma unroll
        for (int off = 1; off <= 32; off <<= 1) p += __shfl_xor(p, off, 64);
        if (lane == r) keep = p;
    }
    atomicAdd(&oacc[b * Dm + w * 64 + lane], wexp * keep);   // one coalesced 64-lane atomic
}

// One block per global node: normalize o, then WO projection (wave-per-row).
// den==0 <=> no in-edges -> output row 0 (matches reference).
__global__ __launch_bounds__(256)
void k_final(const float* __restrict__ oacc, const float* __restrict__ den,
             const float* __restrict__ WO, float* __restrict__ out) {
    int b = blockIdx.x, t = threadIdx.x, w = t >> 6, lane = t & 63;
    __shared__ float so[Dm];
    float dv = den[b * Hh + w];                // head of element t is t>>6
    float ov = oacc[b * Dm + t];
    so[t] = dv > 0.f ? ov / dv : 0.f;
    __syncthreads();
    float4 xa = reinterpret_cast<const float4*>(so)[lane];
    float keep = 0.f;
#pragma unroll 4
    for (int r = 0; r < 64; ++r) {
        float4 ww = reinterpret_cast<const float4*>(WO + (size_t)(w * 64 + r) * Dm)[lane];
        float p = dot4(ww, xa);
#pragma unroll
        for (int off = 1; off <= 32; off <<= 1) p += __shfl_xor(p, off, 64);
        if (lane == r) keep = p;
    }
    out[b * Dm + w * 64 + lane] = keep;
}

extern "C" void kernel_launch(void* const* d_in, const int* in_sizes, int n_in,
                              void* d_out, int out_size, void* d_ws, size_t ws_size,
                              hipStream_t stream) {
    const float* query = (const float*)d_in[0];
    const float* x     = (const float*)d_in[1];
    const float* WQ    = (const float*)d_in[2];
    const float* WK    = (const float*)d_in[3];
    const float* WV    = (const float*)d_in[4];
    const float* WO    = (const float*)d_in[5];
    const int*   src   = (const int*)d_in[6];
    const int*   dst   = (const int*)d_in[7];
    const int*   glob  = (const int*)d_in[8];

    int B  = in_sizes[8];
    int NV = in_sizes[1] / Dm;
    int NE = in_sizes[6];

    // ws layout: Q[B*Dm] | inv[NV] | bcnt[B] | bucket[B*CAP] | oacc[B*Dm] | den[B*Hh]
    float* Q      = (float*)d_ws;
    int*   inv    = (int*)(Q + (size_t)B * Dm);
    int*   bcnt   = inv + NV;
    int*   bucket = bcnt + B;
    float* oacc   = (float*)(bucket + (size_t)B * CAP);
    float* den    = oacc + (size_t)B * Dm;
    float* out    = (float*)d_out;

    int initN = NV > B * Dm ? NV : B * Dm;
    k_init<<<(initN + 255) / 256, 256, 0, stream>>>(inv, NV, bcnt, B, oacc, den);
    k_qproj<<<B, 256, 0, stream>>>(query, WQ, glob, Q, inv);
    k_compact<<<(NE + 255) / 256, 256, 0, stream>>>(src, dst, inv, bcnt, bucket, NE);
    k_kv<<<B * CAP, 256, 0, stream>>>(x, WK, WV, Q, bcnt, bucket, oacc, den);
    k_final<<<B, 256, 0, stream>>>(oacc, den, WO, out);
}

// Round 5
// 131.904 us; speedup vs baseline: 1.8445x; 1.2575x over previous
//
#include <hip/hip_runtime.h>

// DecoderAttention, round 5. Only edges into the B=64 global nodes matter
// (~512 / 320000). Key change vs round 4 (k_kv 49us, latency-bound streaming
// 128KB of WK/WV per edge): move ALL weight math off the per-edge path using
// linearity of the projections:
//   score:  s[e,h] = (WK_h^T q_h) . x_e          (qk precomputed per (b,h))
//   value:  sum_e alpha * (WV_h x_e) = WV_h . (sum_e alpha * x_e)
// Per edge we now touch only the 1KB x row + L2-hot qk. 3 launches total.

#define Dm 256
#define Hh 4

__device__ __forceinline__ float dot4(float4 a, float4 b) {
    return a.x * b.x + a.y * b.y + a.z * b.z + a.w * b.w;
}
__device__ __forceinline__ float wredsum(float p) {
#pragma unroll
    for (int off = 1; off <= 32; off <<= 1) p += __shfl_xor(p, off, 64);
    return p;
}

// Blocks [0, B*H): compute qk[b,h,:] = (1/8) * WK_h^T (WQ_h query_b).
// Blocks [B*H, ...): zero xbar and den (ws is poisoned to 0xAA each call).
__global__ __launch_bounds__(256)
void k_prep(const float* __restrict__ query, const float* __restrict__ WQ,
            const float* __restrict__ WK, float* __restrict__ qk,
            float* __restrict__ xbar, float* __restrict__ den, int B) {
    int t = threadIdx.x, w = t >> 6, lane = t & 63;
    if ((int)blockIdx.x >= B * Hh) {
        int zi = ((int)blockIdx.x - B * Hh) * 256 + t;
        if (zi < B * Hh * Dm) xbar[zi] = 0.f;
        if (zi < B * Hh) den[zi] = 0.f;
        return;
    }
    int b = blockIdx.x / Hh, h = blockIdx.x % Hh;
    __shared__ float sQ[64];
    __shared__ float4 spart[4][64];
    float4 qa = reinterpret_cast<const float4*>(query + (size_t)b * Dm)[lane];
    // Phase 1: Qh[r] = WQ[h*64+r,:] . query[b]; wave w does rows w*16..w*16+15.
#pragma unroll 4
    for (int i = 0; i < 16; ++i) {
        int r = w * 16 + i;
        float4 ww = reinterpret_cast<const float4*>(WQ + (size_t)(h * 64 + r) * Dm)[lane];
        float p = wredsum(dot4(ww, qa));
        if (lane == 0) sQ[r] = p;
    }
    __syncthreads();
    // Phase 2: qk[c] = sum_r Qh[r] * WK[h*64+r, c]; wave w sums its 16 rows,
    // lane owns columns 4*lane..4*lane+3 (coalesced row loads).
    float4 acc = make_float4(0.f, 0.f, 0.f, 0.f);
#pragma unroll 4
    for (int i = 0; i < 16; ++i) {
        int r = w * 16 + i;
        float qv = sQ[r];
        float4 kw = reinterpret_cast<const float4*>(WK + (size_t)(h * 64 + r) * Dm)[lane];
        acc.x += qv * kw.x; acc.y += qv * kw.y; acc.z += qv * kw.z; acc.w += qv * kw.w;
    }
    spart[w][lane] = acc;
    __syncthreads();
    if (t < 64) {
        float4 s0 = spart[0][t], s1 = spart[1][t], s2 = spart[2][t], s3 = spart[3][t];
        float4 s = make_float4((s0.x + s1.x + s2.x + s3.x) * 0.125f,   // fold 1/sqrt(DK)
                               (s0.y + s1.y + s2.y + s3.y) * 0.125f,
                               (s0.z + s1.z + s2.z + s3.z) * 0.125f,
                               (s0.w + s1.w + s2.w + s3.w) * 0.125f);
        reinterpret_cast<float4*>(qk + (size_t)(b * Hh + h) * Dm)[t] = s;
    }
}

// Scan all edges; for dst in glob set, wave-cooperatively accumulate
// exp(qk_h . x_src) and exp(..)*x_src into den / xbar via atomics.
__global__ __launch_bounds__(256)
void k_edges(const int* __restrict__ src, const int* __restrict__ dst,
             const int* __restrict__ glob, const float* __restrict__ x,
             const float* __restrict__ qk, float* __restrict__ xbar,
             float* __restrict__ den, int B, int ne) {
    int t = threadIdx.x, lane = t & 63;
    __shared__ int sglob[256];
    if (t < B) sglob[t] = glob[t];
    __syncthreads();
    int e = blockIdx.x * 256 + t;
    int b = -1;
    int d = (e < ne) ? dst[e] : -1;
    for (int j = 0; j < B; ++j)
        if (sglob[j] == d) b = j;
    int svl = (b >= 0) ? src[e] : 0;
    unsigned long long mask = __ballot(b >= 0);
    while (mask) {
        int j = __ffsll(mask) - 1;
        mask &= mask - 1;
        int eb = __shfl(b, j, 64);
        int es = __shfl(svl, j, 64);
        float4 xa = reinterpret_cast<const float4*>(x + (size_t)es * Dm)[lane];
#pragma unroll
        for (int h = 0; h < Hh; ++h) {
            float4 q4 = reinterpret_cast<const float4*>(qk + (size_t)(eb * Hh + h) * Dm)[lane];
            float p = wredsum(dot4(q4, xa));
            float wexp = __expf(p);            // |s| small: softmax w/o max shift
            if (lane == 0) atomicAdd(&den[eb * Hh + h], wexp);
            float* xb = xbar + (size_t)(eb * Hh + h) * Dm + lane * 4;
            atomicAdd(xb + 0, wexp * xa.x);
            atomicAdd(xb + 1, wexp * xa.y);
            atomicAdd(xb + 2, wexp * xa.z);
            atomicAdd(xb + 3, wexp * xa.w);
        }
    }
}

// Per global node: obar[j] = WV[j,:] . (xbar[h]/den[h]), then out = WO . obar.
// 1024 threads = 16 waves; each wave does 16 coalesced row-dots per phase.
__global__ __launch_bounds__(1024)
void k_final(const float* __restrict__ xbar, const float* __restrict__ den,
             const float* __restrict__ WV, const float* __restrict__ WO,
             float* __restrict__ out) {
    int b = blockIdx.x, t = threadIdx.x, w = t >> 6, lane = t & 63;
    __shared__ float sx[Hh * Dm];
    __shared__ float sobar[Dm];
    if (t < Hh * Dm) {
        int h = t >> 8;
        float dv = den[b * Hh + h];
        sx[t] = dv > 0.f ? xbar[(size_t)(b * Hh + h) * Dm + (t & 255)] / dv : 0.f;
    }
    __syncthreads();
#pragma unroll 4
    for (int i = 0; i < 16; ++i) {
        int j = w * 16 + i;                      // output row 0..255, head j>>6
        float4 wv = reinterpret_cast<const float4*>(WV + (size_t)j * Dm)[lane];
        float4 xb = reinterpret_cast<const float4*>(sx + (j >> 6) * Dm)[lane];
        float p = wredsum(dot4(wv, xb));
        if (lane == 0) sobar[j] = p;
    }
    __syncthreads();
#pragma unroll 4
    for (int i = 0; i < 16; ++i) {
        int j = w * 16 + i;
        float4 wo = reinterpret_cast<const float4*>(WO + (size_t)j * Dm)[lane];
        float4 ob = reinterpret_cast<const float4*>(sobar)[lane];
        float p = wredsum(dot4(wo, ob));
        if (lane == 0) out[(size_t)b * Dm + j] = p;
    }
}

extern "C" void kernel_launch(void* const* d_in, const int* in_sizes, int n_in,
                              void* d_out, int out_size, void* d_ws, size_t ws_size,
                              hipStream_t stream) {
    const float* query = (const float*)d_in[0];
    const float* x     = (const float*)d_in[1];
    const float* WQ    = (const float*)d_in[2];
    const float* WK    = (const float*)d_in[3];
    const float* WV    = (const float*)d_in[4];
    const float* WO    = (const float*)d_in[5];
    const int*   src   = (const int*)d_in[6];
    const int*   dst   = (const int*)d_in[7];
    const int*   glob  = (const int*)d_in[8];

    int B  = in_sizes[8];
    int NE = in_sizes[6];

    // ws layout (floats): qk[B*H*Dm] | den[B*H] | xbar[B*H*Dm]
    float* qk   = (float*)d_ws;
    float* den  = qk + (size_t)B * Hh * Dm;
    float* xbar = den + (size_t)B * Hh;
    float* out  = (float*)d_out;

    int zblocks = (B * Hh * Dm + 255) / 256;          // zeroing blocks
    k_prep<<<B * Hh + zblocks, 256, 0, stream>>>(query, WQ, WK, qk, xbar, den, B);
    k_edges<<<(NE + 255) / 256, 256, 0, stream>>>(src, dst, glob, x, qk, xbar, den, B, NE);
    k_final<<<B, 1024, 0, stream>>>(xbar, den, WV, WO, out);
}